// Round 4
// baseline (390.512 us; speedup 1.0000x reference)
//
#include <hip/hip_runtime.h>

// InstantNGP hash-grid forward, fp32 — single pass, dedup'd gathers,
// L1-bypass via volatile (compiler-tracked; no inline asm after R3 crash).
//
// Per-level constants (symbolically verified vs reference _level_consts()):
//   res   = 16 << l ; scale = res-1 ; mask = (1 << min(12+3l,19)) - 1
//   levels 0-2  : linear, strides [1, res, res^2]
//   levels 3-11 : hash (primes 1, 2654435761, 805459861)
//   levels 12-14: linear, z-stride wrapped to 0 (uint32) -> 4 unique corners
//   level  15   : strides [1, 2^19, 0] -> slot = x & mask -> 2 unique corners
//
// R2 evidence: time tracks ACTIVE lane-requests (~2.8 cy each), independent
// of L2/HBM residency. So (a) drop mathematically-duplicate gathers (-14%),
// (b) volatile gathers -> sc0 (L1 bypass) to test if L1 miss-handling is the
// per-request serializer.

static constexpr int N_PTS = 500000;

typedef float f4 __attribute__((ext_vector_type(4)));

__global__ __launch_bounds__(256) void hashgrid_fwd(
    const float* __restrict__ coords,   // [N,3]
    const float* __restrict__ table,    // [T,4]
    float* __restrict__ out)            // [N,64]
{
    const unsigned t = blockIdx.x * 256u + threadIdx.x;
    const unsigned n = t >> 4;    // point
    const unsigned l = t & 15u;   // level
    if (n >= (unsigned)N_PTS) return;

    const float cx = coords[n * 3 + 0];
    const float cy = coords[n * 3 + 1];
    const float cz = coords[n * 3 + 2];

    const unsigned res = 16u << l;
    const float scale = (float)(res - 1u);

    // pos = c*scale + 0.5, no fma contraction (match np fp32 floor boundaries)
    const float px = __fadd_rn(__fmul_rn(cx, scale), 0.5f);
    const float py = __fadd_rn(__fmul_rn(cy, scale), 0.5f);
    const float pz = __fadd_rn(__fmul_rn(cz, scale), 0.5f);
    const float bxf = floorf(px), byf = floorf(py), bzf = floorf(pz);
    const float fx = __fsub_rn(px, bxf);
    const float fy = __fsub_rn(py, byf);
    const float fz = __fsub_rn(pz, bzf);
    const unsigned x = (unsigned)(int)bxf;
    const unsigned y = (unsigned)(int)byf;
    const unsigned z = (unsigned)(int)bzf;

    const unsigned mask = (l >= 3u) ? 0x7FFFFu : ((1u << (12u + 3u * l)) - 1u);

    // trilinear weights, corner c = (dx<<2)|(dy<<1)|dz
    const float gx = 1.0f - fx, gy = 1.0f - fy, gz = 1.0f - fz;
    float w[8];
    w[0] = gx * gy * gz;
    w[1] = gx * gy * fz;
    w[2] = gx * fy * gz;
    w[3] = gx * fy * fz;
    w[4] = fx * gy * gz;
    w[5] = fx * gy * fz;
    w[6] = fx * fy * gz;
    w[7] = fx * fy * fz;

    unsigned uslot[8];
    float uw[8];
    int nc;
    if (l < 3u) {                       // linear, full strides
        const unsigned zs = res * res;
        const unsigned b = x + y * res + z * zs;
        uslot[0] = (b)                 & mask;  uw[0] = w[0];
        uslot[1] = (b + zs)            & mask;  uw[1] = w[1];
        uslot[2] = (b + res)           & mask;  uw[2] = w[2];
        uslot[3] = (b + res + zs)      & mask;  uw[3] = w[3];
        uslot[4] = (b + 1u)            & mask;  uw[4] = w[4];
        uslot[5] = (b + 1u + zs)       & mask;  uw[5] = w[5];
        uslot[6] = (b + 1u + res)      & mask;  uw[6] = w[6];
        uslot[7] = (b + 1u + res + zs) & mask;  uw[7] = w[7];
        nc = 8;
    } else if (l < 12u) {               // hash
        const unsigned hx0 = x,                  hx1 = x + 1u;
        const unsigned hy0 = y * 2654435761u,    hy1 = (y + 1u) * 2654435761u;
        const unsigned hz0 = z * 805459861u,     hz1 = (z + 1u) * 805459861u;
        uslot[0] = (hx0 ^ hy0 ^ hz0) & mask;  uw[0] = w[0];
        uslot[1] = (hx0 ^ hy0 ^ hz1) & mask;  uw[1] = w[1];
        uslot[2] = (hx0 ^ hy1 ^ hz0) & mask;  uw[2] = w[2];
        uslot[3] = (hx0 ^ hy1 ^ hz1) & mask;  uw[3] = w[3];
        uslot[4] = (hx1 ^ hy0 ^ hz0) & mask;  uw[4] = w[4];
        uslot[5] = (hx1 ^ hy0 ^ hz1) & mask;  uw[5] = w[5];
        uslot[6] = (hx1 ^ hy1 ^ hz0) & mask;  uw[6] = w[6];
        uslot[7] = (hx1 ^ hy1 ^ hz1) & mask;  uw[7] = w[7];
        nc = 8;
    } else if (l < 15u) {               // linear, z-stride wrapped to 0
        const unsigned b = x + y * res;
        uslot[0] = (b)            & mask;  uw[0] = w[0] + w[1];
        uslot[1] = (b + res)      & mask;  uw[1] = w[2] + w[3];
        uslot[2] = (b + 1u)       & mask;  uw[2] = w[4] + w[5];
        uslot[3] = (b + 1u + res) & mask;  uw[3] = w[6] + w[7];
        nc = 4;
    } else {                            // l==15: slot depends on x only
        uslot[0] = (x)      & mask;  uw[0] = (w[0] + w[1]) + (w[2] + w[3]);
        uslot[1] = (x + 1u) & mask;  uw[1] = (w[4] + w[5]) + (w[6] + w[7]);
        nc = 2;
    }

    // Batch-issue gathers (separate loop from FMAs so they pipeline), volatile
    // -> sc0: bypass L1, compiler still tracks vmcnt for us.
    f4 e[8];
    const volatile f4* tp = (const volatile f4*)table;
    #pragma unroll
    for (int c = 0; c < 8; ++c) {
        if (c < nc) {
            e[c] = tp[uslot[c]];
        }
    }

    float a0 = 0.f, a1 = 0.f, a2 = 0.f, a3 = 0.f;
    #pragma unroll
    for (int c = 0; c < 8; ++c) {
        if (c < nc) {
            a0 = fmaf(uw[c], e[c].x, a0);
            a1 = fmaf(uw[c], e[c].y, a1);
            a2 = fmaf(uw[c], e[c].z, a2);
            a3 = fmaf(uw[c], e[c].w, a3);
        }
    }

    float* op = out + (size_t)n * 64u + (size_t)l * 4u;
    __builtin_nontemporal_store(a0, op + 0);
    __builtin_nontemporal_store(a1, op + 1);
    __builtin_nontemporal_store(a2, op + 2);
    __builtin_nontemporal_store(a3, op + 3);
}

extern "C" void kernel_launch(void* const* d_in, const int* in_sizes, int n_in,
                              void* d_out, int out_size, void* d_ws, size_t ws_size,
                              hipStream_t stream) {
    const float* coords = (const float*)d_in[0];
    const float* table  = (const float*)d_in[1];
    float* out = (float*)d_out;

    const int n = in_sizes[0] / 3;                // 500000
    const int total = n * 16;
    const int blocks = (total + 255) / 256;       // 31250
    hipLaunchKernelGGL(hashgrid_fwd, dim3(blocks), dim3(256), 0, stream,
                       coords, table, out);
}

// Round 6
// 259.450 us; speedup vs baseline: 1.5052x; 1.5052x over previous
//
#include <hip/hip_runtime.h>

// InstantNGP hash-grid forward, fp32 — corner-per-lane layout.
//
// 8 lanes per (point, level), one corner per lane, dx = lane bit 0 so
// dx-pairs sit in adjacent lanes (same 64B line 75% for linear levels),
// and duplicate slots at l>=12 (z-stride 0 from uint32 wrap; l15 y-stride
// 2^19 vanishes under &mask) coalesce via same-address broadcast.
// Per-corner weighted value reduced over the 8 lanes by shfl_xor butterfly.
//
// Level constants (verified vs reference _level_consts(), empirically by R4):
//   res = 16<<l ; mask = (1<<min(12+3l,19))-1
//   l 0-2  : linear, strides [1, res, res^2]
//   l 3-11 : hash (primes 1, 2654435761, 805459861)
//   l 12-15: linear, strides [1, res, 0]   (wrap/break in ref stride loop)
//
// No inline-asm VMEM (R3/R5 lesson: untracked async loads corrupt registers).

static constexpr int N_PTS = 500000;

typedef float f4 __attribute__((ext_vector_type(4)));

__global__ __launch_bounds__(256) void hashgrid_fwd(
    const float* __restrict__ coords,   // [N,3]
    const float* __restrict__ table,    // [T,4]
    float* __restrict__ out)            // [N,64]
{
    const unsigned tid = threadIdx.x;
    const unsigned p = tid >> 7;          // local point (0..1)
    const unsigned l = (tid >> 3) & 15u;  // level
    const unsigned c = tid & 7u;          // corner
    const unsigned dx = c & 1u;
    const unsigned dy = (c >> 1) & 1u;
    const unsigned dz = c >> 2;

    const unsigned n = blockIdx.x * 2u + p;

    const float cx = coords[(size_t)n * 3u + 0u];
    const float cy = coords[(size_t)n * 3u + 1u];
    const float cz = coords[(size_t)n * 3u + 2u];

    const unsigned res = 16u << l;
    const float scale = (float)(res - 1u);

    // pos = c*scale + 0.5, no fma contraction (match np fp32 floor boundaries)
    const float px = __fadd_rn(__fmul_rn(cx, scale), 0.5f);
    const float py = __fadd_rn(__fmul_rn(cy, scale), 0.5f);
    const float pz = __fadd_rn(__fmul_rn(cz, scale), 0.5f);
    const float bxf = floorf(px), byf = floorf(py), bzf = floorf(pz);
    const float fx = __fsub_rn(px, bxf);
    const float fy = __fsub_rn(py, byf);
    const float fz = __fsub_rn(pz, bzf);
    const unsigned x = (unsigned)(int)bxf + dx;
    const unsigned y = (unsigned)(int)byf + dy;
    const unsigned z = (unsigned)(int)bzf + dz;

    const unsigned mask = (l >= 3u) ? 0x7FFFFu : ((1u << (12u + 3u * l)) - 1u);

    // this lane's trilinear weight, product order matches np.prod (x*y*z)
    const float wx = dx ? fx : (1.0f - fx);
    const float wy = dy ? fy : (1.0f - fy);
    const float wz = dz ? fz : (1.0f - fz);
    const float w = wx * wy * wz;

    unsigned slot;
    if (l >= 3u && l < 12u) {           // hash levels
        slot = (x ^ (y * 2654435761u) ^ (z * 805459861u)) & mask;
    } else {                            // linear levels
        const unsigned zs = (l < 3u) ? res * res : 0u;   // l>=12: z-stride 0
        slot = (x + y * res + z * zs) & mask;            // uint32 wrap = ref
    }

    const f4 e = *(const f4*)(table + (size_t)slot * 4u);
    float r0 = w * e.x;
    float r1 = w * e.y;
    float r2 = w * e.z;
    float r3 = w * e.w;

    // butterfly reduce over the 8 corner lanes
    #pragma unroll
    for (int m = 1; m <= 4; m <<= 1) {
        r0 += __shfl_xor(r0, m, 64);
        r1 += __shfl_xor(r1, m, 64);
        r2 += __shfl_xor(r2, m, 64);
        r3 += __shfl_xor(r3, m, 64);
    }

    if (c == 0u) {
        f4 o; o.x = r0; o.y = r1; o.z = r2; o.w = r3;
        __builtin_nontemporal_store(o, (f4*)(out + (size_t)n * 64u + (size_t)l * 4u));
    }
}

extern "C" void kernel_launch(void* const* d_in, const int* in_sizes, int n_in,
                              void* d_out, int out_size, void* d_ws, size_t ws_size,
                              hipStream_t stream) {
    const float* coords = (const float*)d_in[0];
    const float* table  = (const float*)d_in[1];
    float* out = (float*)d_out;

    const int blocks = N_PTS / 2;   // 2 points per 256-thread block
    hipLaunchKernelGGL(hashgrid_fwd, dim3(blocks), dim3(256), 0, stream,
                       coords, table, out);
}